// Round 17
// baseline (400.667 us; speedup 1.0000x reference)
//
#include <hip/hip_runtime.h>

// PocketGNN on MI355X — round 12.
// HYPOTHESIS (R4-R11 evidence): edge_gemm floor is scattered-atomic throughput
// (~5M 4B atomicMax RMWs/dispatch; invariant across all other fixes).
// FIX: pad each dst's sorted edge run to a multiple of 16 with DUPLICATE edges
// (max is idempotent) so every 16-edge lane-window has exactly ONE dst.
// Per-window meta (dst | is_last | windows_before) -> epilogue: tree-max 16,
// 2-step shfl merge of same-dst windows within the tile, then:
//   run fully tile-local -> exclusive PLAIN STORE ; else atomicMax.
// ~2.3M stores + ~0.6M atomics replace 5M atomics. +43% MFMA (util was 13%).
// A-gather: one row per window (8x less A traffic).
// Rest as R11: f16 node outputs, dbuf LDS, lgkm-only barriers, XCD swizzle.

#define NN 10000
#define NE 160000
#define NG 64
#define NP 10048   // nodes padded to 64
#define EB 64      // edges per tile
#define TPB 5      // tiles per block
#define NBLK2 969  // capacity blocks: 969*5*64 = 310080 >= 160000+15*10000
#define CAPE (NBLK2 * TPB * 64)
#define CAPW (CAPE / 16)

typedef __attribute__((ext_vector_type(8))) _Float16 f16x8;
typedef __attribute__((ext_vector_type(4))) _Float16 f16x4;
typedef __attribute__((ext_vector_type(4))) float f32x4;

// lgkm-only barrier: orders LDS across waves, leaves vmem (atomics/gathers) in flight
#define LGKM_BARRIER() asm volatile("s_waitcnt lgkmcnt(0)\n\ts_barrier" ::: "memory")

// ---------------- padded-edge-list init ----------------
__global__ void init_pad(int* __restrict__ se3, unsigned* __restrict__ meta) {
    const int i0 = blockIdx.x * blockDim.x + threadIdx.x;
    const int stride = gridDim.x * blockDim.x;
    for (int j = i0; j < CAPE; j += stride) se3[j] = 0;
    for (int j = i0; j < CAPW; j += stride) meta[j] = ((unsigned)NN << 5) | 16u;  // sentinel
}

// ---------------- edge sort by dst (counting sort, padded) ----------------
__global__ void hist_kernel(const int* __restrict__ dstI, int* __restrict__ hist) {
    int i = blockIdx.x * blockDim.x + threadIdx.x;
    if (i < NE) atomicAdd(&hist[dstI[i]], 1);
}

// exclusive scan over PADDED degrees; emits pstart, working cursor, total E'
__global__ void scan_kernel(const int* __restrict__ hist, int* __restrict__ pstart,
                            int* __restrict__ cursor, int* __restrict__ einfo) {
    __shared__ int sums[256];
    const int t = threadIdx.x;
    const int per = (NN + 255) / 256;  // 40
    const int lo = t * per, hi = (lo + per < NN) ? lo + per : NN;
    int s = 0;
    for (int i = lo; i < hi; ++i) s += (hist[i] + 15) & ~15;
    sums[t] = s;
    __syncthreads();
    for (int ofs = 1; ofs < 256; ofs <<= 1) {
        int add = (t >= ofs) ? sums[t - ofs] : 0;
        __syncthreads();
        sums[t] += add;
        __syncthreads();
    }
    int run = sums[t] - s;  // exclusive prefix
    for (int i = lo; i < hi; ++i) {
        const int p = (hist[i] + 15) & ~15;
        pstart[i] = run;
        cursor[i] = run;
        run += p;
    }
    if (t == 255) einfo[0] = run;  // padded edge count E'
}

__global__ void scatter_kernel(const int* __restrict__ srcI, const int* __restrict__ dstI,
                               int* __restrict__ cursor, int* __restrict__ se3) {
    int i = blockIdx.x * blockDim.x + threadIdx.x;
    if (i < NE) {
        int p = atomicAdd(&cursor[dstI[i]], 1);
        se3[p] = srcI[i];
    }
}

// duplicate-fill pad slots; write per-window meta = (d<<5)|(is_last<<4)|min(wbm,15)
__global__ void fill_meta(const int* __restrict__ hist, const int* __restrict__ pstart,
                          int* __restrict__ se3, unsigned* __restrict__ meta) {
    const int i0 = blockIdx.x * blockDim.x + threadIdx.x;
    for (int d = i0; d < NN; d += gridDim.x * blockDim.x) {
        const int deg = hist[d];
        if (deg == 0) continue;
        const int st = pstart[d];
        const int padded = (deg + 15) & ~15;
        const int s0 = se3[st];  // any edge of d works: max is idempotent
        for (int i = deg; i < padded; ++i) se3[st + i] = s0;
        const int nwin = padded >> 4;
        const int w0 = st >> 4;
        for (int j = 0; j < nwin; ++j)
            meta[w0 + j] = ((unsigned)d << 5) | ((j == nwin - 1) ? 16u : 0u)
                         | (unsigned)(j < 15 ? j : 15);
    }
}

// ---------------- weight prep ----------------
// WcT [512][C]: rows 0..255 = (w1t-w1b)^T, 256..511 = w1b^T.  w2T [256][256] = w2^T.
__global__ void prep_weights(const float* __restrict__ w1, const float* __restrict__ w2, int C,
                             _Float16* __restrict__ WcT, _Float16* __restrict__ w2T) {
    int total1 = 512 * C;
    int total = total1 + 256 * 256;
    for (int i = blockIdx.x * blockDim.x + threadIdx.x; i < total; i += gridDim.x * blockDim.x) {
        if (i < total1) {
            int n = i / C, k = i - n * C;
            float v = (n < 256) ? (w1[k * 256 + n] - w1[(C + k) * 256 + n])
                                : w1[(C + k) * 256 + (n - 256)];
            WcT[n * C + k] = (_Float16)v;
        } else {
            int j = i - total1;
            int n = j >> 8, k = j & 255;
            w2T[n * 256 + k] = (_Float16)w2[k * 256 + n];
        }
    }
}

// ---------------- node GEMM: [A | B] = x @ [Wc_A | Wc_B]; both f16 (A gets +b1) --------
template <int C>
__global__ __launch_bounds__(256, 2) void node_gemm(
    const float* __restrict__ xf, const _Float16* __restrict__ WT,
    const float* __restrict__ b1, _Float16* __restrict__ Afh, _Float16* __restrict__ Bh) {
    const int wave = threadIdx.x >> 6, lane = threadIdx.x & 63;
    const int lrow = lane & 15, lk = (lane >> 4) * 8;
    const int r0 = blockIdx.x * 64;
    const int c0 = blockIdx.y * 256 + wave * 64;

    f32x4 acc[4][4] = {};
#pragma unroll
    for (int kk = 0; kk < C; kk += 32) {
        f16x8 ah[4];
#pragma unroll
        for (int m = 0; m < 4; ++m) {
            int rc = r0 + m * 16 + lrow;
            if (rc > NN - 1) rc = NN - 1;
            const float* xp = xf + (size_t)rc * C + kk + lk;
            const float4 v0 = *(const float4*)(xp);
            const float4 v1 = *(const float4*)(xp + 4);
            f16x8 a;
            a[0] = (_Float16)v0.x; a[1] = (_Float16)v0.y;
            a[2] = (_Float16)v0.z; a[3] = (_Float16)v0.w;
            a[4] = (_Float16)v1.x; a[5] = (_Float16)v1.y;
            a[6] = (_Float16)v1.z; a[7] = (_Float16)v1.w;
            ah[m] = a;
        }
#pragma unroll
        for (int t = 0; t < 4; ++t) {
            f16x8 bh = *(const f16x8*)(WT + (size_t)(c0 + t * 16 + lrow) * C + kk + lk);
#pragma unroll
            for (int m = 0; m < 4; ++m)
                acc[m][t] = __builtin_amdgcn_mfma_f32_16x16x32_f16(ah[m], bh, acc[m][t], 0, 0, 0);
        }
    }
    if (blockIdx.y == 0) {  // A half: +bias (f32), store f16
#pragma unroll
        for (int t = 0; t < 4; ++t) {
            const int col = c0 + t * 16 + lrow;
            const float bias = b1[col];
#pragma unroll
            for (int m = 0; m < 4; ++m)
#pragma unroll
                for (int j = 0; j < 4; ++j) {
                    const int row = r0 + m * 16 + (lane >> 4) * 4 + j;
                    Afh[(size_t)row * 256 + col] = (_Float16)(acc[m][t][j] + bias);
                }
        }
    } else {  // B half: f16
#pragma unroll
        for (int t = 0; t < 4; ++t) {
            const int col = c0 - 256 + t * 16 + lrow;
#pragma unroll
            for (int m = 0; m < 4; ++m)
#pragma unroll
                for (int j = 0; j < 4; ++j) {
                    const int row = r0 + m * 16 + (lane >> 4) * 4 + j;
                    Bh[(size_t)row * 256 + col] = (_Float16)acc[m][t][j];
                }
        }
    }
}

// ---------------- fused edge kernel: padded windows, store-dominant epilogue ----------
__global__ __launch_bounds__(512, 2) void edge_gemm(
    const _Float16* __restrict__ Afh, const _Float16* __restrict__ Bh,
    const int* __restrict__ se3, const unsigned* __restrict__ meta,
    const int* __restrict__ einfo,
    const _Float16* __restrict__ w2T,
    const float* __restrict__ b2, float* __restrict__ y) {
    __shared__ _Float16 hh[2 * EB * 256];  // 64 KB double buffer, XOR-swizzled
    const int tid = threadIdx.x;
    const int wave = tid >> 6, lane = tid & 63;
    const int lrow = lane & 15, lk = (lane >> 4) * 8;

    // XCD-chunked bijective swizzle over 969 blocks (= 8*121 + 1)
    const int orig = blockIdx.x;
    const int xcd = orig & 7, pos = orig >> 3;
    const int qq = NBLK2 >> 3, rr = NBLK2 & 7;  // 121, 1
    const int bid = (xcd < rr ? xcd * (qq + 1) : rr * (qq + 1) + (xcd - rr) * qq) + pos;
    const int t0 = bid * TPB;

    const int ep = einfo[0];                 // padded edge count (uniform)
    const int tiles_real = (ep + 63) >> 6;
    if (t0 >= tiles_real) return;            // block-uniform early exit
    const int ntt = (tiles_real - t0 < TPB) ? (tiles_real - t0) : TPB;

    const _Float16* wbase = w2T + (size_t)(wave * 32 + lrow) * 256 + lk;
    const float bias0 = b2[wave * 32 + lrow];
    const float bias1 = b2[wave * 32 + 16 + lrow];

    f16x4 av, bv[8];

    auto stage_issue = [&](int tile) {
        int dw = (int)(meta[tile * 4 + (wave >> 1)] >> 5);
        if (dw >= NN) dw = 0;  // sentinel window: harmless gather
        int se[8];
#pragma unroll
        for (int i = 0; i < 8; ++i) se[i] = se3[tile * EB + wave * 8 + i];
        av = *(const f16x4*)(Afh + (size_t)dw * 256 + lane * 4);  // ONE A-row per window
#pragma unroll
        for (int i = 0; i < 8; ++i)
            bv[i] = *(const f16x4*)(Bh + (size_t)se[i] * 256 + lane * 4);
    };
    auto stage_write = [&](int buf) {
#pragma unroll
        for (int i = 0; i < 8; ++i) {
            const int el = wave * 8 + i;  // block-local edge 0..63
            const int row = ((el >> 2) & 3) * 16 + (el >> 4) * 4 + (el & 3);
            f16x4 h = av + bv[i];
#pragma unroll
            for (int k = 0; k < 4; ++k) h[k] = h[k] > (_Float16)0.f ? h[k] : (_Float16)0.f;
            *(f16x4*)(&hh[buf * (EB * 256) + ((row * 256 + lane * 4) ^ ((row & 15) << 3))]) = h;
        }
    };

    stage_issue(t0);
    stage_write(0);
    LGKM_BARRIER();

    for (int tt = 0; tt < ntt; ++tt) {
        const int tile = t0 + tt;
        const int hbase = (tt & 1) * (EB * 256);

        if (tt + 1 < ntt) stage_issue(tile + 1);  // gathers fly during GEMM

        // ---- GEMM: M=64 (4 tiles) x N=32 (2 tiles), K=256; bh streams from L2 ----
        f32x4 acc[4][2] = {};
#pragma unroll
        for (int q = 0; q < 8; ++q) {
            f16x8 bh0 = *(const f16x8*)(wbase + q * 32);
            f16x8 bh1 = *(const f16x8*)(wbase + 16 * 256 + q * 32);
            f16x8 ah[4];
#pragma unroll
            for (int m = 0; m < 4; ++m) {
                const int row = m * 16 + lrow;
                const int idx = (row * 256 + q * 32 + lk) ^ ((row & 15) << 3);
                ah[m] = *(const f16x8*)(&hh[hbase + idx]);
            }
#pragma unroll
            for (int m = 0; m < 4; ++m) {
                acc[m][0] = __builtin_amdgcn_mfma_f32_16x16x32_f16(ah[m], bh0, acc[m][0], 0, 0, 0);
                acc[m][1] = __builtin_amdgcn_mfma_f32_16x16x32_f16(ah[m], bh1, acc[m][1], 0, 0, 0);
            }
        }

        if (tt + 1 < ntt) stage_write((tt + 1) & 1);
        LGKM_BARRIER();  // LDS ordered; vmem stays in flight

        // ---- epilogue: one dst per 16-edge window; shfl-merge; stores >> atomics ----
        {
            const int g = lane >> 4;
            const unsigned mt = meta[tile * 4 + g];
            const int d = (int)(mt >> 5);
            const int lastw = (int)((mt >> 4) & 1u);
            const int wbm = (int)(mt & 15u);
#pragma unroll
            for (int t = 0; t < 2; ++t) {
                const float bias = t ? bias1 : bias0;
                const int col = wave * 32 + t * 16 + lrow;
                float v = acc[0][t][0];
#pragma unroll
                for (int k = 1; k < 16; ++k) v = fmaxf(v, acc[k >> 2][t][k & 3]);
                // 2-step prefix merge of same-dst consecutive windows (within tile)
                float pv = __shfl(v, (lane - 16) & 63);
                int pd = __shfl(d, (lane - 16) & 63);
                if (g >= 1 && pd == d) v = fmaxf(v, pv);
                float pv2 = __shfl(v, (lane - 32) & 63);
                int pd2 = __shfl(d, (lane - 32) & 63);
                if (g >= 2 && pd2 == d) v = fmaxf(v, pv2);
                if (d < NN) {
                    const float o = v + bias;
                    if (lastw && wbm <= g) {
                        // run fully inside this tile and merged -> exclusive store
                        y[(size_t)d * 256 + col] = fmaxf(o, 0.f);
                    } else if ((lastw && wbm > g) || (!lastw && g == 3)) {
                        if (o > 0.f)
                            atomicMax((int*)(y + (size_t)d * 256 + col), __float_as_int(o));
                    }
                    // else: absorbed by a later quarter in this tile
                }
            }
        }
    }
}

// ---------------- per-graph mean+max pool (4 row-slices per block) ----------------
__global__ void pool_kernel(const float* __restrict__ y, const int* __restrict__ batch,
                            float* __restrict__ pooled) {
    const int g = blockIdx.x;
    __shared__ int slo, shi;
    __shared__ float ssum[4][256];
    __shared__ float smax[4][256];
    const int c = threadIdx.x, ry = threadIdx.y;
    if (c == 0 && ry == 0) {
        int lo = 0, hi = NN;
        while (lo < hi) { int m = (lo + hi) >> 1; if (batch[m] < g) lo = m + 1; else hi = m; }
        slo = lo;
        int lo2 = lo, hi2 = NN;
        while (lo2 < hi2) { int m = (lo2 + hi2) >> 1; if (batch[m] < g + 1) lo2 = m + 1; else hi2 = m; }
        shi = lo2;
    }
    __syncthreads();
    const int lo = slo, hi = shi;
    float s = 0.f, mx = 0.f;  // y >= 0 -> 0 safe identity
    for (int n = lo + ry; n < hi; n += 4) {
        const float v = y[(size_t)n * 256 + c];
        s += v;
        mx = fmaxf(mx, v);
    }
    ssum[ry][c] = s;
    smax[ry][c] = mx;
    __syncthreads();
    if (ry == 0) {
        const float st = (ssum[0][c] + ssum[1][c]) + (ssum[2][c] + ssum[3][c]);
        const float mt = fmaxf(fmaxf(smax[0][c], smax[1][c]), fmaxf(smax[2][c], smax[3][c]));
        const int cnt = hi - lo;
        pooled[g * 512 + c] = cnt ? st / (float)cnt : 0.f;
        pooled[g * 512 + 256 + c] = cnt ? mt : 0.f;
    }
}

// ---------------- classifier MLP ----------------
__global__ void classifier(const float* __restrict__ pooled,
                           const float* __restrict__ w1, const float* __restrict__ b1,
                           const float* __restrict__ w2, const float* __restrict__ b2,
                           const float* __restrict__ w3, const float* __restrict__ b3,
                           float* __restrict__ out) {
    const int g = blockIdx.x;
    __shared__ float ph[512];
    __shared__ float o1[256];
    __shared__ float o2[64];
    const int t = threadIdx.x;  // 256 threads
    ph[t] = pooled[g * 512 + t];
    ph[t + 256] = pooled[g * 512 + 256 + t];
    __syncthreads();
    float s = 0.f;
    for (int k = 0; k < 512; ++k) s += ph[k] * w1[k * 256 + t];
    o1[t] = fmaxf(s + b1[t], 0.f);
    __syncthreads();
    if (t < 64) {
        float s2 = 0.f;
        for (int k = 0; k < 256; ++k) s2 += o1[k] * w2[k * 64 + t];
        o2[t] = fmaxf(s2 + b2[t], 0.f);
    }
    __syncthreads();
    if (t < 64) {
        float v = o2[t] * w3[t];
        for (int off = 32; off; off >>= 1) v += __shfl_down(v, off);
        if (t == 0) out[g] = v + b3[0];
    }
}

extern "C" void kernel_launch(void* const* d_in, const int* in_sizes, int n_in,
                              void* d_out, int out_size, void* d_ws, size_t ws_size,
                              hipStream_t stream) {
    (void)in_sizes; (void)n_in; (void)out_size; (void)ws_size;
    const float* x0 = (const float*)d_in[0];
    const int* eidx = (const int*)d_in[1];
    const int* batch = (const int*)d_in[2];
    const int* srcI = eidx;            // edge_index[0] = src
    const int* dstI = eidx + NE;       // edge_index[1] = dst

    char* ws = (char*)d_ws;
    size_t off = 0;
    auto alloc = [&](size_t bytes) -> void* {
        void* p = ws + off;
        off += (bytes + 255) & ~(size_t)255;
        return p;
    };
    _Float16* Afh = (_Float16*)alloc((size_t)NP * 256 * 2);
    _Float16* Bh  = (_Float16*)alloc((size_t)NP * 256 * 2);
    float* y  = (float*)alloc((size_t)NP * 256 * 4);
    _Float16* WcT = (_Float16*)alloc(512 * 256 * 2);
    _Float16* w2T = (_Float16*)alloc(256 * 256 * 2);
    float* pooled = (float*)alloc(64 * 512 * 4);
    int* hist   = (int*)alloc(NN * 4);
    int* pstart = (int*)alloc(NN * 4);
    int* cursor = (int*)alloc(NN * 4);
    int* einfo  = (int*)alloc(256);
    int* se3    = (int*)alloc((size_t)CAPE * 4);
    unsigned* meta = (unsigned*)alloc((size_t)CAPW * 4);

    const float* lw[3][4] = {
        {(const float*)d_in[3],  (const float*)d_in[4],  (const float*)d_in[5],  (const float*)d_in[6]},
        {(const float*)d_in[7],  (const float*)d_in[8],  (const float*)d_in[9],  (const float*)d_in[10]},
        {(const float*)d_in[11], (const float*)d_in[12], (const float*)d_in[13], (const float*)d_in[14]},
    };

    // padded dst-sorted edge list (once, reused all layers)
    init_pad<<<dim3(512), dim3(256), 0, stream>>>(se3, meta);
    hipMemsetAsync(hist, 0, NN * 4, stream);
    hist_kernel<<<dim3((NE + 255) / 256), dim3(256), 0, stream>>>(dstI, hist);
    scan_kernel<<<dim3(1), dim3(256), 0, stream>>>(hist, pstart, cursor, einfo);
    scatter_kernel<<<dim3((NE + 255) / 256), dim3(256), 0, stream>>>(srcI, dstI, cursor, se3);
    fill_meta<<<dim3(40), dim3(256), 0, stream>>>(hist, pstart, se3, meta);

    for (int l = 0; l < 3; ++l) {
        const int C = (l == 0) ? 128 : 256;
        prep_weights<<<dim3(256), dim3(256), 0, stream>>>(lw[l][0], lw[l][2], C, WcT, w2T);
        if (C == 128)
            node_gemm<128><<<dim3(NP / 64, 2), dim3(256), 0, stream>>>(x0, WcT, lw[l][1], Afh, Bh);
        else
            node_gemm<256><<<dim3(NP / 64, 2), dim3(256), 0, stream>>>(y, WcT, lw[l][1], Afh, Bh);
        hipMemsetAsync(y, 0, (size_t)NP * 256 * 4, stream);
        edge_gemm<<<dim3(NBLK2), dim3(512), 0, stream>>>(Afh, Bh, se3, meta, einfo, w2T, lw[l][3], y);
    }

    pool_kernel<<<dim3(NG), dim3(256, 4), 0, stream>>>(y, batch, pooled);
    classifier<<<dim3(NG), dim3(256), 0, stream>>>(pooled,
        (const float*)d_in[15], (const float*)d_in[16],
        (const float*)d_in[17], (const float*)d_in[18],
        (const float*)d_in[19], (const float*)d_in[20], (float*)d_out);
}

// Round 18
// 373.811 us; speedup vs baseline: 1.0718x; 1.0718x over previous
//
#include <hip/hip_runtime.h>

// PocketGNN on MI355X — round 13.
// R12 lesson: store-dominant epilogue cut per-tile cost ~35-40%, but pad-16 added
// +47% tiles (and a ragged 2-round occupancy), netting a loss. R13 keeps the
// store-dominant idea with ZERO padding: edges dst-sorted => any dst that is not
// the first/last dst of a tile is fully contained in it -> exclusive plain store.
// Only <=2 boundary dsts per tile use atomicMax. Segmented shfl-carry merges runs
// across lane-quarters. 2500 tiles, 500 blocks, all co-resident, one round.
// - node_gemm: single pass (512 thr, 8 waves x N64, M=32): activations read once.
// - pool+classifier fused.
// - Rest as R11: f16 A/B, dbuf LDS, lgkm-only barriers, XCD swizzle, (512,2).

#define NN 10000
#define NE 160000
#define NG 64
#define NP 10048  // nodes padded to 64
#define EB 64     // edges per tile
#define TPB 5     // tiles per block
#define NBLK 500  // 2500 tiles / 5

typedef __attribute__((ext_vector_type(8))) _Float16 f16x8;
typedef __attribute__((ext_vector_type(4))) _Float16 f16x4;
typedef __attribute__((ext_vector_type(4))) float f32x4;

#define LGKM_BARRIER() asm volatile("s_waitcnt lgkmcnt(0)\n\ts_barrier" ::: "memory")
#define NEG_INF (-1e30f)

// ---------------- edge sort by dst (counting sort) ----------------
__global__ void hist_kernel(const int* __restrict__ dstI, int* __restrict__ hist) {
    int i = blockIdx.x * blockDim.x + threadIdx.x;
    if (i < NE) atomicAdd(&hist[dstI[i]], 1);
}

// in-place safe: cursor may alias hist
__global__ void scan_kernel(const int* __restrict__ hist, int* __restrict__ cursor) {
    __shared__ int sums[256];
    const int t = threadIdx.x;
    const int per = (NN + 255) / 256;  // 40
    const int lo = t * per, hi = (lo + per < NN) ? lo + per : NN;
    int s = 0;
    for (int i = lo; i < hi; ++i) s += hist[i];
    sums[t] = s;
    __syncthreads();
    for (int ofs = 1; ofs < 256; ofs <<= 1) {
        int add = (t >= ofs) ? sums[t - ofs] : 0;
        __syncthreads();
        sums[t] += add;
        __syncthreads();
    }
    int run = sums[t] - s;  // exclusive prefix
    for (int i = lo; i < hi; ++i) {
        int h = hist[i];      // read BEFORE aliased write
        cursor[i] = run;
        run += h;
    }
}

__global__ void scatter_kernel(const int* __restrict__ srcI, const int* __restrict__ dstI,
                               int* __restrict__ cursor,
                               int* __restrict__ se2, int* __restrict__ de2) {
    int i = blockIdx.x * blockDim.x + threadIdx.x;
    if (i < NE) {
        int d = dstI[i];
        int p = atomicAdd(&cursor[d], 1);
        se2[p] = srcI[i];
        de2[p] = d;
    }
}

// ---------------- weight prep ----------------
// WcT [512][C]: rows 0..255 = (w1t-w1b)^T, 256..511 = w1b^T.  w2T [256][256] = w2^T.
__global__ void prep_weights(const float* __restrict__ w1, const float* __restrict__ w2, int C,
                             _Float16* __restrict__ WcT, _Float16* __restrict__ w2T) {
    int total1 = 512 * C;
    int total = total1 + 256 * 256;
    for (int i = blockIdx.x * blockDim.x + threadIdx.x; i < total; i += gridDim.x * blockDim.x) {
        if (i < total1) {
            int n = i / C, k = i - n * C;
            float v = (n < 256) ? (w1[k * 256 + n] - w1[(C + k) * 256 + n])
                                : w1[(C + k) * 256 + (n - 256)];
            WcT[n * C + k] = (_Float16)v;
        } else {
            int j = i - total1;
            int n = j >> 8, k = j & 255;
            w2T[n * 256 + k] = (_Float16)w2[k * 256 + n];
        }
    }
}

// ---------------- node GEMM: [A | B] = x @ [Wc_A | Wc_B]; both f16 (A gets +b1) --------
// Single pass: 512 thr / 8 waves; wave w covers cols w*64..w*64+63; M=32 rows/block.
// Activations (f32) read once; inline f16 convert; rows clamped (pad never gathered).
template <int C>
__global__ __launch_bounds__(512, 2) void node_gemm(
    const float* __restrict__ xf, const _Float16* __restrict__ WT,
    const float* __restrict__ b1, _Float16* __restrict__ Afh, _Float16* __restrict__ Bh) {
    const int wave = threadIdx.x >> 6, lane = threadIdx.x & 63;
    const int lrow = lane & 15, lk = (lane >> 4) * 8;
    const int r0 = blockIdx.x * 32;
    const int c0 = wave * 64;

    f32x4 acc[2][4] = {};
#pragma unroll
    for (int kk = 0; kk < C; kk += 32) {
        f16x8 ah[2];
#pragma unroll
        for (int m = 0; m < 2; ++m) {
            int rc = r0 + m * 16 + lrow;
            if (rc > NN - 1) rc = NN - 1;
            const float* xp = xf + (size_t)rc * C + kk + lk;
            const float4 v0 = *(const float4*)(xp);
            const float4 v1 = *(const float4*)(xp + 4);
            f16x8 a;
            a[0] = (_Float16)v0.x; a[1] = (_Float16)v0.y;
            a[2] = (_Float16)v0.z; a[3] = (_Float16)v0.w;
            a[4] = (_Float16)v1.x; a[5] = (_Float16)v1.y;
            a[6] = (_Float16)v1.z; a[7] = (_Float16)v1.w;
            ah[m] = a;
        }
#pragma unroll
        for (int t = 0; t < 4; ++t) {
            f16x8 bh = *(const f16x8*)(WT + (size_t)(c0 + t * 16 + lrow) * C + kk + lk);
#pragma unroll
            for (int m = 0; m < 2; ++m)
                acc[m][t] = __builtin_amdgcn_mfma_f32_16x16x32_f16(ah[m], bh, acc[m][t], 0, 0, 0);
        }
    }
    if (wave < 4) {  // A half: +bias (f32), store f16
#pragma unroll
        for (int t = 0; t < 4; ++t) {
            const int col = c0 + t * 16 + lrow;
            const float bias = b1[col];
#pragma unroll
            for (int m = 0; m < 2; ++m)
#pragma unroll
                for (int j = 0; j < 4; ++j) {
                    const int row = r0 + m * 16 + (lane >> 4) * 4 + j;
                    Afh[(size_t)row * 256 + col] = (_Float16)(acc[m][t][j] + bias);
                }
        }
    } else {  // B half: f16
#pragma unroll
        for (int t = 0; t < 4; ++t) {
            const int col = c0 - 256 + t * 16 + lrow;
#pragma unroll
            for (int m = 0; m < 2; ++m)
#pragma unroll
                for (int j = 0; j < 4; ++j) {
                    const int row = r0 + m * 16 + (lane >> 4) * 4 + j;
                    Bh[(size_t)row * 256 + col] = (_Float16)acc[m][t][j];
                }
        }
    }
}

// ---------------- fused edge kernel: interior-store epilogue ----------------
__global__ __launch_bounds__(512, 2) void edge_gemm(
    const _Float16* __restrict__ Afh, const _Float16* __restrict__ Bh,
    const int* __restrict__ se2, const int* __restrict__ de2,
    const _Float16* __restrict__ w2T,
    const float* __restrict__ b2, float* __restrict__ y) {
    __shared__ _Float16 hh[2 * EB * 256];  // 64 KB double buffer, XOR-swizzled
    const int tid = threadIdx.x;
    const int wave = tid >> 6, lane = tid & 63;
    const int lrow = lane & 15, lk = (lane >> 4) * 8;

    // XCD-chunked bijective swizzle over 500 blocks (= 8*62 + 4)
    const int orig = blockIdx.x;
    const int xcd = orig & 7, pos = orig >> 3;
    const int qq = NBLK >> 3, rr = NBLK & 7;  // 62, 4
    const int bid = (xcd < rr ? xcd * (qq + 1) : rr * (qq + 1) + (xcd - rr) * qq) + pos;
    const int t0 = bid * TPB;

    const _Float16* wbase = w2T + (size_t)(wave * 32 + lrow) * 256 + lk;
    const float bias0 = b2[wave * 32 + lrow];
    const float bias1 = b2[wave * 32 + 16 + lrow];

    f16x4 av[8], bv[8];

    auto stage_issue = [&](int tile) {
        int se[8], de[8];
#pragma unroll
        for (int i = 0; i < 8; ++i) {
            const int e = tile * EB + wave * 8 + i;
            se[i] = se2[e];
            de[i] = de2[e];
        }
#pragma unroll
        for (int i = 0; i < 8; ++i) {
            bv[i] = *(const f16x4*)(Bh + (size_t)se[i] * 256 + lane * 4);
            av[i] = *(const f16x4*)(Afh + (size_t)de[i] * 256 + lane * 4);
        }
    };
    auto stage_write = [&](int buf) {
#pragma unroll
        for (int i = 0; i < 8; ++i) {
            const int el = wave * 8 + i;
            const int row = ((el >> 2) & 3) * 16 + (el >> 4) * 4 + (el & 3);
            f16x4 h = av[i] + bv[i];
#pragma unroll
            for (int k = 0; k < 4; ++k) h[k] = h[k] > (_Float16)0.f ? h[k] : (_Float16)0.f;
            *(f16x4*)(&hh[buf * (EB * 256) + ((row * 256 + lane * 4) ^ ((row & 15) << 3))]) = h;
        }
    };

    stage_issue(t0);
    stage_write(0);
    LGKM_BARRIER();

    for (int tt = 0; tt < TPB; ++tt) {
        const int tile = t0 + tt;
        const int hbase = (tt & 1) * (EB * 256);

        if (tt + 1 < TPB) stage_issue(tile + 1);  // gathers fly during GEMM

        // ---- GEMM: M=64 x N=32 per wave, K=256; bh streams from L2 ----
        f32x4 acc[4][2] = {};
#pragma unroll
        for (int q = 0; q < 8; ++q) {
            f16x8 bh0 = *(const f16x8*)(wbase + q * 32);
            f16x8 bh1 = *(const f16x8*)(wbase + 16 * 256 + q * 32);
            f16x8 ah[4];
#pragma unroll
            for (int m = 0; m < 4; ++m) {
                const int row = m * 16 + lrow;
                const int idx = (row * 256 + q * 32 + lk) ^ ((row & 15) << 3);
                ah[m] = *(const f16x8*)(&hh[hbase + idx]);
            }
#pragma unroll
            for (int m = 0; m < 4; ++m) {
                acc[m][0] = __builtin_amdgcn_mfma_f32_16x16x32_f16(ah[m], bh0, acc[m][0], 0, 0, 0);
                acc[m][1] = __builtin_amdgcn_mfma_f32_16x16x32_f16(ah[m], bh1, acc[m][1], 0, 0, 0);
            }
        }

        if (tt + 1 < TPB) stage_write((tt + 1) & 1);
        LGKM_BARRIER();  // LDS ordered; vmem (gathers/atomics) stays in flight

        // ---- epilogue: lane quarter g owns edges tile*64+g*16..+15 (consecutive) ----
        // Interior dst (not first/last dst of tile) -> run fully inside tile -> STORE.
        // Boundary dst -> atomicMax. Segmented shfl-carry merges runs across quarters.
        {
            const int g = lane >> 4;
            const int e0 = tile * EB;
            int d[16];
#pragma unroll
            for (int k = 0; k < 16; ++k) d[k] = de2[e0 + g * 16 + k];
            const int head_d = d[0], tail_d = d[15];
            bool uni = true;
#pragma unroll
            for (int k = 0; k < 15; ++k) uni = uni && (d[k] == d[15]);

            const int pt = __shfl(tail_d, (lane - 16) & 63);
            const bool conn = (g > 0) && (pt == head_d);      // run continues from g-1
            const int ucv = (int)(uni && conn);
            const int uc1 = __shfl(ucv, (lane - 16) & 63);
            const bool reach2 = conn && (uc1 != 0);
            const int uc2 = __shfl(ucv, (lane - 32) & 63);
            const bool reach3 = reach2 && (uc2 != 0);
            const int nh = __shfl(head_d, (lane + 16) & 63);
            const bool own_tail = (g == 3) || (nh != tail_d); // else downstream owns
            const int thead = __shfl(head_d, 0);              // tile's first dst
            const int ttail = __shfl(tail_d, 63);             // tile's last dst

#pragma unroll
            for (int t = 0; t < 2; ++t) {
                const float bias = t ? bias1 : bias0;
                const int col = wave * 32 + t * 16 + lrow;
                float a[16];
#pragma unroll
                for (int k = 0; k < 16; ++k) a[k] = acc[k >> 2][t][k & 3];
                // trailing-run max (dst == tail_d entries are exactly the trailing run)
                float tmax = NEG_INF;
#pragma unroll
                for (int k = 0; k < 16; ++k) if (d[k] == tail_d) tmax = fmaxf(tmax, a[k]);
                const float tm1 = __shfl(tmax, (lane - 16) & 63);
                const float tm2 = __shfl(tmax, (lane - 32) & 63);
                const float tm3 = __shfl(tmax, (lane - 48) & 63);
                float carry = NEG_INF;
                if (conn) carry = tm1;
                if (reach2) carry = fmaxf(carry, tm2);
                if (reach3) carry = fmaxf(carry, tm3);

                auto emit = [&](int dd, float v) {
                    const float o = v + bias;
                    if (dd == thead || dd == ttail) {
                        if (o > 0.f)
                            atomicMax((int*)(y + (size_t)dd * 256 + col), __float_as_int(o));
                    } else {
                        y[(size_t)dd * 256 + col] = fmaxf(o, 0.f);
                    }
                };

                float run = fmaxf(a[0], carry);
#pragma unroll
                for (int k = 1; k < 16; ++k) {
                    if (d[k] == d[k - 1]) {
                        run = fmaxf(run, a[k]);
                    } else {
                        emit(d[k - 1], run);
                        run = a[k];
                    }
                }
                if (own_tail) emit(tail_d, run);
            }
        }
    }
}

// ---------------- fused per-graph pool + classifier ----------------
__global__ void pool_classifier(const float* __restrict__ y, const int* __restrict__ batch,
                                const float* __restrict__ w1, const float* __restrict__ b1,
                                const float* __restrict__ w2, const float* __restrict__ b2,
                                const float* __restrict__ w3, const float* __restrict__ b3,
                                float* __restrict__ out) {
    const int g = blockIdx.x;
    __shared__ int slo, shi;
    __shared__ float ssum[4][256];
    __shared__ float smax[4][256];
    __shared__ float ph[512];
    __shared__ float o1[256];
    __shared__ float o2[64];
    const int c = threadIdx.x, ry = threadIdx.y;
    if (c == 0 && ry == 0) {
        int lo = 0, hi = NN;
        while (lo < hi) { int m = (lo + hi) >> 1; if (batch[m] < g) lo = m + 1; else hi = m; }
        slo = lo;
        int lo2 = lo, hi2 = NN;
        while (lo2 < hi2) { int m = (lo2 + hi2) >> 1; if (batch[m] < g + 1) lo2 = m + 1; else hi2 = m; }
        shi = lo2;
    }
    __syncthreads();
    const int lo = slo, hi = shi;
    float s = 0.f, mx = 0.f;  // y >= 0 -> 0 safe identity
    for (int n = lo + ry; n < hi; n += 4) {
        const float v = y[(size_t)n * 256 + c];
        s += v;
        mx = fmaxf(mx, v);
    }
    ssum[ry][c] = s;
    smax[ry][c] = mx;
    __syncthreads();
    if (ry == 0) {
        const float st = (ssum[0][c] + ssum[1][c]) + (ssum[2][c] + ssum[3][c]);
        const float mt = fmaxf(fmaxf(smax[0][c], smax[1][c]), fmaxf(smax[2][c], smax[3][c]));
        const int cnt = hi - lo;
        ph[c] = cnt ? st / (float)cnt : 0.f;
        ph[256 + c] = cnt ? mt : 0.f;
    }
    __syncthreads();
    if (ry == 0) {
        float s1 = 0.f;
        for (int k = 0; k < 512; ++k) s1 += ph[k] * w1[k * 256 + c];
        o1[c] = fmaxf(s1 + b1[c], 0.f);
    }
    __syncthreads();
    if (ry == 0 && c < 64) {
        float s2 = 0.f;
        for (int k = 0; k < 256; ++k) s2 += o1[k] * w2[k * 64 + c];
        o2[c] = fmaxf(s2 + b2[c], 0.f);
    }
    __syncthreads();
    if (ry == 0 && c < 64) {
        float v = o2[c] * w3[c];
        for (int off = 32; off; off >>= 1) v += __shfl_down(v, off);
        if (c == 0) out[g] = v + b3[0];
    }
}

extern "C" void kernel_launch(void* const* d_in, const int* in_sizes, int n_in,
                              void* d_out, int out_size, void* d_ws, size_t ws_size,
                              hipStream_t stream) {
    (void)in_sizes; (void)n_in; (void)out_size; (void)ws_size;
    const float* x0 = (const float*)d_in[0];
    const int* eidx = (const int*)d_in[1];
    const int* batch = (const int*)d_in[2];
    const int* srcI = eidx;            // edge_index[0] = src
    const int* dstI = eidx + NE;       // edge_index[1] = dst

    char* ws = (char*)d_ws;
    size_t off = 0;
    auto alloc = [&](size_t bytes) -> void* {
        void* p = ws + off;
        off += (bytes + 255) & ~(size_t)255;
        return p;
    };
    _Float16* Afh = (_Float16*)alloc((size_t)NP * 256 * 2);
    _Float16* Bh  = (_Float16*)alloc((size_t)NP * 256 * 2);
    float* y  = (float*)alloc((size_t)NP * 256 * 4);
    _Float16* WcT = (_Float16*)alloc(512 * 256 * 2);
    _Float16* w2T = (_Float16*)alloc(256 * 256 * 2);
    int* hist = (int*)alloc(NN * 4);
    int* se2 = (int*)alloc(NE * 4);
    int* de2 = (int*)alloc(NE * 4);

    const float* lw[3][4] = {
        {(const float*)d_in[3],  (const float*)d_in[4],  (const float*)d_in[5],  (const float*)d_in[6]},
        {(const float*)d_in[7],  (const float*)d_in[8],  (const float*)d_in[9],  (const float*)d_in[10]},
        {(const float*)d_in[11], (const float*)d_in[12], (const float*)d_in[13], (const float*)d_in[14]},
    };

    // sort edges by dst (once, reused all layers)
    hipMemsetAsync(hist, 0, NN * 4, stream);
    hist_kernel<<<dim3((NE + 255) / 256), dim3(256), 0, stream>>>(dstI, hist);
    scan_kernel<<<dim3(1), dim3(256), 0, stream>>>(hist, hist);  // in-place exclusive scan
    scatter_kernel<<<dim3((NE + 255) / 256), dim3(256), 0, stream>>>(srcI, dstI, hist, se2, de2);

    for (int l = 0; l < 3; ++l) {
        const int C = (l == 0) ? 128 : 256;
        prep_weights<<<dim3(256), dim3(256), 0, stream>>>(lw[l][0], lw[l][2], C, WcT, w2T);
        if (C == 128)
            node_gemm<128><<<dim3(NP / 32), dim3(512), 0, stream>>>(x0, WcT, lw[l][1], Afh, Bh);
        else
            node_gemm<256><<<dim3(NP / 32), dim3(512), 0, stream>>>(y, WcT, lw[l][1], Afh, Bh);
        hipMemsetAsync(y, 0, (size_t)NP * 256 * 4, stream);
        edge_gemm<<<dim3(NBLK), dim3(512), 0, stream>>>(Afh, Bh, se2, de2, w2T, lw[l][3], y);
    }

    pool_classifier<<<dim3(NG), dim3(256, 4), 0, stream>>>(y, batch,
        (const float*)d_in[15], (const float*)d_in[16],
        (const float*)d_in[17], (const float*)d_in[18],
        (const float*)d_in[19], (const float*)d_in[20], (float*)d_out);
}